// Round 10
// baseline (196.764 us; speedup 1.0000x reference)
//
#include <hip/hip_runtime.h>

// Involution: out[b, g*64+c, ho, wo] = sum_{kh,kw} xp[b, g*64+c, ho+kh, wo+kw] * W[b,g,kh,kw,ho,wo]
// B=8, C=512, G=8, cpg=64, H=W=Ho=Wo=64, K=7, PAD=3. fp32.
//
// R12: kill the structural LDS bank conflict. Evidence: SQ_LDS_BANK_CONFLICT
// = 14.16M constant across R4-R11 (3.1 extra cy per ds_read_b64); LDS-pipe
// accounting ~180K cy/CU ~= 75us of the 88us kernel (~80% busy) -- THE
// shared resource that made R9's occupancy doubling null.
// Root cause: b64 reads must be 8B-aligned -> even word addresses -> only
// the 16 even banks are reachable (wo0=2*tx stride-2 pattern). Inherent; no
// swizzle fixes it without breaking alignment.
// Fix: parity-split row layout. Row r: even wcols at [72r, 72r+36), odd
// wcols at [72r+36, 72r+72). Lane tx's window (wcols 2tx+1..2tx+8) becomes
//   odd-half  words tx..tx+3   (f1,f3,f5,f7)
//   even-half words tx+1..tx+4 (f2,f4,f6,f8)
// -> lane-stride 1, all 32 banks, ZERO conflicts; 4B-aligned b32 reads the
// compiler merges into ds_read2_b32 (4 LDS instrs/ch/kh vs 5, each cheaper).
// Staging float4 quad (wcols 4sq..4sq+3) -> two aligned float2 writes:
//   even-half word 2sq (q.x,q.z), odd-half word 36+2sq (q.y,q.w).
// Everything else identical to R11 (88us): CHPC=8, CSPLIT=8, XCD swizzle,
// waves_per_eu(2,4), weight loads in-loop, no sched_barrier.
// Predict: conflicts 14.16M -> <2M; dur 88 -> 65-78us if LDS-bound.

#define BB 8
#define CC 512
#define GG 8
#define CPG 64
#define HH 64
#define WW 64
#define HW (HH * WW)
#define KK 7
#define PAD 3

#define TILE_ROWS 8
#define CSPLIT 8
#define CHPC 8                           // channels per block
#define LDS_ROWS (TILE_ROWS + KK - 1)    // 14
#define LDS_PITCH 72                     // row pitch in words (36 even + 36 odd)
#define HALF 36                          // odd-half offset within a row
#define CH_STRIDE (LDS_ROWS * LDS_PITCH) // 1008 words per channel plane
#define NQUADS (LDS_ROWS * (LDS_PITCH / 4))  // 252 staging quads per plane

__global__ __launch_bounds__(256)
__attribute__((amdgpu_waves_per_eu(2, 4)))
void involution_kernel(const float* __restrict__ x,
                       const float* __restrict__ weight,
                       float* __restrict__ out) {
    const int tid = threadIdx.x;
    const int tx = tid & 31;          // wo0 = 2*tx
    const int ty = tid >> 5;          // row within tile

    // ---- XCD-locality decode: all 64 sub-blocks of a (b,g) on one XCD ----
    const int f = blockIdx.x;         // 0..4095
    const int xcd = f & 7;
    const int k = f >> 3;             // 0..511
    const int bg = ((k >> 6) << 3) + xcd;   // 0..63, bijective
    const int sub = k & 63;           // 0..63
    const int b = bg >> 3;
    const int g = bg & 7;
    const int tile = sub >> 3;        // 0..7
    const int cs = sub & 7;           // 0..7

    const int wo0 = tx << 1;
    const int hbase = tile * TILE_ROWS;
    const int ho = hbase + ty;

    __shared__ float xs[CHPC * CH_STRIDE];   // 32256 B

    // per-pixel weight base: taps at +t*HW, float2 covers wo0,wo0+1
    const float* wq = weight + ((size_t)(b * GG + g) * (KK * KK)) * HW
                    + ho * WW + wo0;

    // staging geometry (global side unchanged; LDS side parity-split)
    const int sr = tid / 18;              // 0..13 (tid < 252)
    const int sq = tid - sr * 18;         // 0..17
    const int xrow = hbase + sr - PAD;
    const int xcol = sq * 4 - 4;          // -4..64, quad aligned (wcol = 4*sq)
    const bool sval = (tid < NQUADS)
                   && ((unsigned)xrow < HH) && ((unsigned)xcol < WW);
    const int soff = xrow * WW + xcol;
    const int evoff = sr * LDS_PITCH + (sq << 1);          // even-half b64 dest
    const int odoff = sr * LDS_PITCH + HALF + (sq << 1);   // odd-half b64 dest

    const size_t cbase = (size_t)(b * CC + g * CPG + cs * CHPC) * HW;
    const float* xg = x + cbase;
    float* og = out + cbase + ho * WW + wo0;

    // ---- stage 8 channel planes (register pass-through, dead after write) ----
    float4 q[CHPC];
#pragma unroll
    for (int ch = 0; ch < CHPC; ++ch) {
        float4 v = make_float4(0.f, 0.f, 0.f, 0.f);
        if (sval)
            v = *(const float4*)(xg + (size_t)ch * HW + soff);
        q[ch] = v;
    }
    if (tid < NQUADS) {
#pragma unroll
        for (int ch = 0; ch < CHPC; ++ch) {
            const float4 v = q[ch];
            *(float2*)(&xs[ch * CH_STRIDE + evoff]) = make_float2(v.x, v.z);
            *(float2*)(&xs[ch * CH_STRIDE + odoff]) = make_float2(v.y, v.w);
        }
    }
    __syncthreads();                 // planes visible

    // ---- compute: kh outer (7 float2 weights live), ch inner ----
    float acc0[CHPC], acc1[CHPC];
#pragma unroll
    for (int ch = 0; ch < CHPC; ++ch) { acc0[ch] = 0.f; acc1[ch] = 0.f; }

#pragma unroll
    for (int kh = 0; kh < KK; ++kh) {
        float2 wk[KK];
#pragma unroll
        for (int j = 0; j < KK; ++j)
            wk[j] = *(const float2*)(wq + (size_t)(kh * KK + j) * HW);

#pragma unroll
        for (int ch = 0; ch < CHPC; ++ch) {
            const int rb = ch * CH_STRIDE + (ty + kh) * LDS_PITCH;
            const float* oh = &xs[rb + HALF + tx];   // odd wcols 2tx+1..2tx+7
            const float* eh = &xs[rb + tx + 1];      // even wcols 2tx+2..2tx+8
            const float f1 = oh[0], f3 = oh[1], f5 = oh[2], f7 = oh[3];
            const float f2 = eh[0], f4 = eh[1], f6 = eh[2], f8 = eh[3];
            float a0 = acc0[ch], a1 = acc1[ch];
            a0 = fmaf(f1, wk[0].x, a0);  a1 = fmaf(f2, wk[0].y, a1);
            a0 = fmaf(f2, wk[1].x, a0);  a1 = fmaf(f3, wk[1].y, a1);
            a0 = fmaf(f3, wk[2].x, a0);  a1 = fmaf(f4, wk[2].y, a1);
            a0 = fmaf(f4, wk[3].x, a0);  a1 = fmaf(f5, wk[3].y, a1);
            a0 = fmaf(f5, wk[4].x, a0);  a1 = fmaf(f6, wk[4].y, a1);
            a0 = fmaf(f6, wk[5].x, a0);  a1 = fmaf(f7, wk[5].y, a1);
            a0 = fmaf(f7, wk[6].x, a0);  a1 = fmaf(f8, wk[6].y, a1);
            acc0[ch] = a0; acc1[ch] = a1;
        }
    }

    // ---- store 8 channels x 2 pixels ----
#pragma unroll
    for (int ch = 0; ch < CHPC; ++ch) {
        *(float2*)(og + (size_t)ch * HW)
            = make_float2(acc0[ch], acc1[ch]);
    }
}

extern "C" void kernel_launch(void* const* d_in, const int* in_sizes, int n_in,
                              void* d_out, int out_size, void* d_ws, size_t ws_size,
                              hipStream_t stream) {
    const float* x = (const float*)d_in[0];
    const float* w = (const float*)d_in[1];
    float* out = (float*)d_out;

    dim3 grid((HH / TILE_ROWS) * CSPLIT * GG * BB);   // 4096 blocks, 1D for swizzle
    dim3 block(256);
    involution_kernel<<<grid, block, 0, stream>>>(x, w, out);
}

// Round 11
// 183.795 us; speedup vs baseline: 1.0706x; 1.0706x over previous
//
#include <hip/hip_runtime.h>

// Involution: out[b, g*64+c, ho, wo] = sum_{kh,kw} xp[b, g*64+c, ho+kh, wo+kw] * W[b,g,kh,kw,ho,wo]
// B=8, C=512, G=8, cpg=64, H=W=Ho=Wo=64, K=7, PAD=3. fp32.
//
// R13: manual full weight hoist. Eliminated theories: TLP (R9: 2x occupancy
// -> worse), conflicts (R12: 14.2M->0.79M, dur flat), scheduler-auto-hoist
// (R11: budget open, VGPR 64->68 only, dur flat). Remaining invariant: the
// 7 per-kh weight-load groups, each an exposed ~250cy L2 wait right before
// its FMA block. Fix in source: load ALL 49 float2 weights into registers
// at kernel entry (fully unrolled, compile-time indices -> regs not
// scratch), issued after the x staging loads; latency hides under
// LDS-writes + barrier. Compute loop = pure LDS+FMA, zero global stalls.
// Regs: wkk 98 + q 32 (dead at write) + acc 16 + temps ~25 -> peak ~150
// < 256 budget (waves_per_eu(2,4), R11-verified no-spill).
// Base layout = R12 parity-split (conflict-free ds_read2_b32: even wcols
// in words [0,36), odd in [36,72) per row; lane window = stride-1 in each
// half), which becomes the critical path once weight stalls are gone.
// Tripwires: FETCH/WRITE balloon = spill (abort path); VGPR stuck ~68 =
// hoist defeated.

#define BB 8
#define CC 512
#define GG 8
#define CPG 64
#define HH 64
#define WW 64
#define HW (HH * WW)
#define KK 7
#define PAD 3

#define TILE_ROWS 8
#define CSPLIT 8
#define CHPC 8                           // channels per block
#define LDS_ROWS (TILE_ROWS + KK - 1)    // 14
#define LDS_PITCH 72                     // row pitch in words (36 even + 36 odd)
#define HALF 36                          // odd-half offset within a row
#define CH_STRIDE (LDS_ROWS * LDS_PITCH) // 1008 words per channel plane
#define NQUADS (LDS_ROWS * (LDS_PITCH / 4))  // 252 staging quads per plane

__global__ __launch_bounds__(256)
__attribute__((amdgpu_waves_per_eu(2, 4)))
void involution_kernel(const float* __restrict__ x,
                       const float* __restrict__ weight,
                       float* __restrict__ out) {
    const int tid = threadIdx.x;
    const int tx = tid & 31;          // wo0 = 2*tx
    const int ty = tid >> 5;          // row within tile

    // ---- XCD-locality decode: all 64 sub-blocks of a (b,g) on one XCD ----
    const int f = blockIdx.x;         // 0..4095
    const int xcd = f & 7;
    const int k = f >> 3;             // 0..511
    const int bg = ((k >> 6) << 3) + xcd;   // 0..63, bijective
    const int sub = k & 63;           // 0..63
    const int b = bg >> 3;
    const int g = bg & 7;
    const int tile = sub >> 3;        // 0..7
    const int cs = sub & 7;           // 0..7

    const int wo0 = tx << 1;
    const int hbase = tile * TILE_ROWS;
    const int ho = hbase + ty;

    __shared__ float xs[CHPC * CH_STRIDE];   // 32256 B

    // per-pixel weight base: taps at +t*HW, float2 covers wo0,wo0+1
    const float* wq = weight + ((size_t)(b * GG + g) * (KK * KK)) * HW
                    + ho * WW + wo0;

    // staging geometry (global side; LDS side parity-split)
    const int sr = tid / 18;              // 0..13 (tid < 252)
    const int sq = tid - sr * 18;         // 0..17
    const int xrow = hbase + sr - PAD;
    const int xcol = sq * 4 - 4;          // -4..64, quad aligned (wcol = 4*sq)
    const bool sval = (tid < NQUADS)
                   && ((unsigned)xrow < HH) && ((unsigned)xcol < WW);
    const int soff = xrow * WW + xcol;
    const int evoff = sr * LDS_PITCH + (sq << 1);          // even-half dest
    const int odoff = sr * LDS_PITCH + HALF + (sq << 1);   // odd-half dest

    const size_t cbase = (size_t)(b * CC + g * CPG + cs * CHPC) * HW;
    const float* xg = x + cbase;
    float* og = out + cbase + ho * WW + wo0;

    // ---- issue x staging loads ----
    float4 q[CHPC];
#pragma unroll
    for (int ch = 0; ch < CHPC; ++ch) {
        float4 v = make_float4(0.f, 0.f, 0.f, 0.f);
        if (sval)
            v = *(const float4*)(xg + (size_t)ch * HW + soff);
        q[ch] = v;
    }

    // ---- issue ALL 49 weight loads (latency hides under LDS-write+barrier)
    float2 wkk[KK * KK];
#pragma unroll
    for (int t = 0; t < KK * KK; ++t)
        wkk[t] = *(const float2*)(wq + (size_t)t * HW);

    // ---- parity-split LDS write ----
    if (tid < NQUADS) {
#pragma unroll
        for (int ch = 0; ch < CHPC; ++ch) {
            const float4 v = q[ch];
            *(float2*)(&xs[ch * CH_STRIDE + evoff]) = make_float2(v.x, v.z);
            *(float2*)(&xs[ch * CH_STRIDE + odoff]) = make_float2(v.y, v.w);
        }
    }
    __syncthreads();                 // planes visible

    // ---- compute: pure LDS + FMA, weights all in registers ----
    float acc0[CHPC], acc1[CHPC];
#pragma unroll
    for (int ch = 0; ch < CHPC; ++ch) { acc0[ch] = 0.f; acc1[ch] = 0.f; }

#pragma unroll
    for (int kh = 0; kh < KK; ++kh) {
#pragma unroll
        for (int ch = 0; ch < CHPC; ++ch) {
            const int rb = ch * CH_STRIDE + (ty + kh) * LDS_PITCH;
            const float* oh = &xs[rb + HALF + tx];   // odd wcols 2tx+1..2tx+7
            const float* eh = &xs[rb + tx + 1];      // even wcols 2tx+2..2tx+8
            const float f1 = oh[0], f3 = oh[1], f5 = oh[2], f7 = oh[3];
            const float f2 = eh[0], f4 = eh[1], f6 = eh[2], f8 = eh[3];
            float a0 = acc0[ch], a1 = acc1[ch];
            a0 = fmaf(f1, wkk[kh * KK + 0].x, a0);  a1 = fmaf(f2, wkk[kh * KK + 0].y, a1);
            a0 = fmaf(f2, wkk[kh * KK + 1].x, a0);  a1 = fmaf(f3, wkk[kh * KK + 1].y, a1);
            a0 = fmaf(f3, wkk[kh * KK + 2].x, a0);  a1 = fmaf(f4, wkk[kh * KK + 2].y, a1);
            a0 = fmaf(f4, wkk[kh * KK + 3].x, a0);  a1 = fmaf(f5, wkk[kh * KK + 3].y, a1);
            a0 = fmaf(f5, wkk[kh * KK + 4].x, a0);  a1 = fmaf(f6, wkk[kh * KK + 4].y, a1);
            a0 = fmaf(f6, wkk[kh * KK + 5].x, a0);  a1 = fmaf(f7, wkk[kh * KK + 5].y, a1);
            a0 = fmaf(f7, wkk[kh * KK + 6].x, a0);  a1 = fmaf(f8, wkk[kh * KK + 6].y, a1);
            acc0[ch] = a0; acc1[ch] = a1;
        }
    }

    // ---- store 8 channels x 2 pixels ----
#pragma unroll
    for (int ch = 0; ch < CHPC; ++ch) {
        *(float2*)(og + (size_t)ch * HW)
            = make_float2(acc0[ch], acc1[ch]);
    }
}

extern "C" void kernel_launch(void* const* d_in, const int* in_sizes, int n_in,
                              void* d_out, int out_size, void* d_ws, size_t ws_size,
                              hipStream_t stream) {
    const float* x = (const float*)d_in[0];
    const float* w = (const float*)d_in[1];
    float* out = (float*)d_out;

    dim3 grid((HH / TILE_ROWS) * CSPLIT * GG * BB);   // 4096 blocks, 1D for swizzle
    dim3 block(256);
    involution_kernel<<<grid, block, 0, stream>>>(x, w, out);
}

// Round 13
// 175.834 us; speedup vs baseline: 1.1190x; 1.0453x over previous
//
#include <hip/hip_runtime.h>

// Involution: out[b, g*64+c, ho, wo] = sum_{kh,kw} xp[b, g*64+c, ho+kh, wo+kw] * W[b,g,kh,kw,ho,wo]
// B=8, C=512, G=8, cpg=64, H=W=Ho=Wo=64, K=7, PAD=3. fp32.
//
// R14 (resubmit; prior round hit the broker's "container failed twice" --
// audited: no divergent barriers, no loops, all indices bounds-checked, so
// not kernel-side): 4 px/thread on a quad-split LDS layout. R13 (83us)
// removed the last exposed global latency (weights hoisted, VGPR 92, no
// spill); residual = per-FMA overhead (LDS instrs + addressing + per-block
// amortization) vs the ~42us pure-FMA floor. 4px/thread improves every
// ratio 1.6-2x:
//   - quad-split rows: pc stored by (pc&3) in four 18-word quarters.
//     Thread window pc=4tx+1..4tx+10 -> 3 stride-1 runs -> 10 b32 reads
//     (paired to ~5 ds_read2_b32), banks 8ty+18r+tx = 2 lanes/bank = FREE
//     (m136). Same mechanism R12 validated (14.2M->0.79M), mod-4 version.
//     NOT R10's refuted b128 pattern.
//   - 10 LDS dwords per 28 FMA (was 8 per 14); staging + 49 weight loads
//     amortize over 1568 FMA/thread (was 784).
//   - weights: float4 taps, kh-double-buffered wka/wkb (56 regs) -- full
//     hoist would be 196 regs. R5's design, now under the PROVEN open
//     budget (waves_per_eu(2,4); R13 measured 92/256, zero spill).
// Geometry: 16tx x 16ty, TILE_ROWS=16, CHPC=8, CSPLIT=8, grid 2048,
// R8's XCD swizzle. LDS 50688B -> 3 blocks/CU.
// Tripwire: FETCH/WRITE balloon = spill -> abort to R13 + CHPC=16.

#define BB 8
#define CC 512
#define GG 8
#define CPG 64
#define HH 64
#define WW 64
#define HW (HH * WW)
#define KK 7
#define PAD 3

#define TILE_ROWS 16
#define CSPLIT 8
#define CHPC 8                            // channels per block
#define LDS_ROWS (TILE_ROWS + KK - 1)     // 22
#define LDS_PITCH 72                      // 4 quarters x 18 words
#define QUARTER 18
#define CH_STRIDE (LDS_ROWS * LDS_PITCH)  // 1584 words per channel plane
#define PLANE_QUADS (LDS_ROWS * 18)       // 396 staging quads per plane
#define TOT_QUADS (CHPC * PLANE_QUADS)    // 3168
#define NPASS 13                          // ceil(3168/256)

__global__ __launch_bounds__(256)
__attribute__((amdgpu_waves_per_eu(2, 4)))
void involution_kernel(const float* __restrict__ x,
                       const float* __restrict__ weight,
                       float* __restrict__ out) {
    const int tid = threadIdx.x;
    const int tx = tid & 15;          // wo0 = 4*tx
    const int ty = tid >> 4;          // 0..15, row within tile

    // ---- XCD-locality decode: all 32 sub-blocks of a (b,g) on one XCD ----
    const int f = blockIdx.x;         // 0..2047
    const int xcd = f & 7;
    const int k = f >> 3;             // 0..255
    const int bg = ((k >> 5) << 3) + xcd;   // 0..63, bijective
    const int sub = k & 31;           // 0..31
    const int b = bg >> 3;
    const int g = bg & 7;
    const int tile = sub >> 3;        // 0..3
    const int cs = sub & 7;           // 0..7

    const int wo0 = tx << 2;
    const int hbase = tile * TILE_ROWS;
    const int ho = hbase + ty;

    __shared__ float xs[CHPC * CH_STRIDE];   // 50688 B

    // per-pixel weight base: tap t at +t*HW; float4 covers wo0..wo0+3
    const float* wq = weight + ((size_t)(b * GG + g) * (KK * KK)) * HW
                    + ho * WW + wo0;

    const size_t cbase = (size_t)(b * CC + g * CPG + cs * CHPC) * HW;
    const float* xg = x + cbase;
    float* og = out + cbase + ho * WW + wo0;

    // ---- staging: 3168 quads in 13 masked passes; quad-split LDS writes ----
    float4 sv[NPASS];
    int lofs[NPASS];
    bool act[NPASS];
#pragma unroll
    for (int i = 0; i < NPASS; ++i) {
        const int Q = tid + i * 256;
        act[i] = (Q < TOT_QUADS);
        const int ch = Q / PLANE_QUADS;
        const int rem = Q - ch * PLANE_QUADS;
        const int sr = rem / 18;              // 0..21
        const int sq = rem - sr * 18;         // 0..17
        const int xrow = hbase + sr - PAD;    // -3..66
        const int xcol = (sq << 2) - 4;       // -4..64 (pc = 4*sq + ii)
        const bool ld = act[i]
                     && ((unsigned)xrow < HH) && ((unsigned)xcol < WW);
        float4 v = make_float4(0.f, 0.f, 0.f, 0.f);
        if (ld)
            v = *(const float4*)(xg + (size_t)ch * HW + xrow * WW + xcol);
        sv[i] = v;
        lofs[i] = ch * CH_STRIDE + sr * LDS_PITCH + sq;
    }

    // ---- kh=0 weight taps (latency hides under LDS writes + barrier) ----
    float4 wka[KK], wkb[KK];
#pragma unroll
    for (int j = 0; j < KK; ++j)
        wka[j] = *(const float4*)(wq + (size_t)j * HW);

#pragma unroll
    for (int i = 0; i < NPASS; ++i) {
        if (act[i]) {
            xs[lofs[i]]               = sv[i].x;   // pc%4==0 quarter
            xs[lofs[i] + QUARTER]     = sv[i].y;
            xs[lofs[i] + 2 * QUARTER] = sv[i].z;
            xs[lofs[i] + 3 * QUARTER] = sv[i].w;
        }
    }
    __syncthreads();                 // planes visible

    // ---- compute: kh unrolled, weights double-buffered, 4 px/thread ----
    float4 acc[CHPC];
#pragma unroll
    for (int ch = 0; ch < CHPC; ++ch)
        acc[ch] = make_float4(0.f, 0.f, 0.f, 0.f);

    // v[d] = x at pc = 4tx+1+d ; pixel p tap j uses v[p+j]
#define KH_STEP(KH, WCUR, WNXT, NKH, LN)                                    \
    {                                                                       \
        if (LN) {                                                           \
            _Pragma("unroll")                                               \
            for (int j = 0; j < KK; ++j)                                    \
                WNXT[j] = *(const float4*)(wq + (size_t)((NKH) * KK + j) * HW); \
        }                                                                   \
        _Pragma("unroll")                                                   \
        for (int ch = 0; ch < CHPC; ++ch) {                                 \
            const int b2 = ch * CH_STRIDE + (ty + (KH)) * LDS_PITCH;        \
            const float v0 = xs[b2 + QUARTER + tx];                         \
            const float v1 = xs[b2 + 2 * QUARTER + tx];                     \
            const float v2 = xs[b2 + 3 * QUARTER + tx];                     \
            const float v3 = xs[b2 + tx + 1];                               \
            const float v4 = xs[b2 + QUARTER + tx + 1];                     \
            const float v5 = xs[b2 + 2 * QUARTER + tx + 1];                 \
            const float v6 = xs[b2 + 3 * QUARTER + tx + 1];                 \
            const float v7 = xs[b2 + tx + 2];                               \
            const float v8 = xs[b2 + QUARTER + tx + 2];                     \
            const float v9 = xs[b2 + 2 * QUARTER + tx + 2];                 \
            float4 a = acc[ch];                                             \
            a.x = fmaf(v0, WCUR[0].x, a.x);  a.y = fmaf(v1, WCUR[0].y, a.y); \
            a.z = fmaf(v2, WCUR[0].z, a.z);  a.w = fmaf(v3, WCUR[0].w, a.w); \
            a.x = fmaf(v1, WCUR[1].x, a.x);  a.y = fmaf(v2, WCUR[1].y, a.y); \
            a.z = fmaf(v3, WCUR[1].z, a.z);  a.w = fmaf(v4, WCUR[1].w, a.w); \
            a.x = fmaf(v2, WCUR[2].x, a.x);  a.y = fmaf(v3, WCUR[2].y, a.y); \
            a.z = fmaf(v4, WCUR[2].z, a.z);  a.w = fmaf(v5, WCUR[2].w, a.w); \
            a.x = fmaf(v3, WCUR[3].x, a.x);  a.y = fmaf(v4, WCUR[3].y, a.y); \
            a.z = fmaf(v5, WCUR[3].z, a.z);  a.w = fmaf(v6, WCUR[3].w, a.w); \
            a.x = fmaf(v4, WCUR[4].x, a.x);  a.y = fmaf(v5, WCUR[4].y, a.y); \
            a.z = fmaf(v6, WCUR[4].z, a.z);  a.w = fmaf(v7, WCUR[4].w, a.w); \
            a.x = fmaf(v5, WCUR[5].x, a.x);  a.y = fmaf(v6, WCUR[5].y, a.y); \
            a.z = fmaf(v7, WCUR[5].z, a.z);  a.w = fmaf(v8, WCUR[5].w, a.w); \
            a.x = fmaf(v6, WCUR[6].x, a.x);  a.y = fmaf(v7, WCUR[6].y, a.y); \
            a.z = fmaf(v8, WCUR[6].z, a.z);  a.w = fmaf(v9, WCUR[6].w, a.w); \
            acc[ch] = a;                                                    \
        }                                                                   \
    }

    KH_STEP(0, wka, wkb, 1, true)
    KH_STEP(1, wkb, wka, 2, true)
    KH_STEP(2, wka, wkb, 3, true)
    KH_STEP(3, wkb, wka, 4, true)
    KH_STEP(4, wka, wkb, 5, true)
    KH_STEP(5, wkb, wka, 6, true)
    KH_STEP(6, wka, wkb, 0, false)
#undef KH_STEP

    // ---- store 8 channels x 4 pixels ----
#pragma unroll
    for (int ch = 0; ch < CHPC; ++ch)
        *(float4*)(og + (size_t)ch * HW) = acc[ch];
}

extern "C" void kernel_launch(void* const* d_in, const int* in_sizes, int n_in,
                              void* d_out, int out_size, void* d_ws, size_t ws_size,
                              hipStream_t stream) {
    const float* x = (const float*)d_in[0];
    const float* w = (const float*)d_in[1];
    float* out = (float*)d_out;

    dim3 grid((HH / TILE_ROWS) * CSPLIT * GG * BB);   // 2048 blocks, 1D for swizzle
    dim3 block(256);
    involution_kernel<<<grid, block, 0, stream>>>(x, w, out);
}